// Round 6
// baseline (453.286 us; speedup 1.0000x reference)
//
#include <hip/hip_runtime.h>

#define NN 2048
#define CC 512
#define BB 4
#define HH 8
#define DD 64
#define SCALE 0.18033688011112043f   // 0.125 * log2(e), folded into Wq/bq

typedef unsigned short u16;
typedef __attribute__((ext_vector_type(8))) short bf16x8;   // 8 bf16 (4 VGPRs)
typedef __attribute__((ext_vector_type(4))) float f32x4;    // MFMA accumulator

extern "C" __device__ float __ocml_exp2_f32(float);

__device__ inline u16 f2b(float x) {           // fp32 -> bf16 (RNE)
    unsigned u = __builtin_bit_cast(unsigned, x);
    u += 0x7fffu + ((u >> 16) & 1u);
    return (u16)(u >> 16);
}
__device__ inline float b2f(u16 h) {
    unsigned u = ((unsigned)h) << 16;
    return __builtin_bit_cast(float, u);
}

#define GLD16(g, l) __builtin_amdgcn_global_load_lds( \
    (const __attribute__((address_space(1))) unsigned int*)(g), \
    (__attribute__((address_space(3))) unsigned int*)(l), 16, 0, 0)

// ---------------------------------------------------------------------------
// GEMM core: tile 128(n) x (JT*32)(o) x 32(k); 4 waves 2x2.
// SWAP=false: A=X rows(n), B=W cols(o) -> C rows=n, cols=o.
// SWAP=true : A=W rows(o), B=X cols(n) -> C rows=o, cols=n  (same LDS reads,
//             only mfma operand order flips; enables o-contiguous epilogue).
// ---------------------------------------------------------------------------
template<int JT, bool SWAP>
__device__ __forceinline__ void gemm_core_t(
    const u16* __restrict__ Xa, const u16* __restrict__ Xb, int Ca, int K,
    const u16* __restrict__ Wt, size_t rowBase,
    u16* As, u16* Bs, f32x4 (&acc)[4][JT])
{
    constexpr int OT = JT * 32;
    const int tid = threadIdx.x;
    const int lane = tid & 63, w = tid >> 6;
    const int quad = lane >> 4, l16 = lane & 15;
    const int wrow = w & 1, wcol = w >> 1;
    const int arow = lane >> 2, aseg = lane & 3;   // 16 rows x 4x16B per GLD set

    for (int k0 = 0; k0 < K; k0 += 32) {
        const u16* Xs; int Crow, cc;
        if (k0 < Ca) { Xs = Xa; Crow = Ca; cc = k0; }
        else         { Xs = Xb; Crow = K - Ca; cc = k0 - Ca; }
#pragma unroll
        for (int i = 0; i < 2; ++i) {
            int rl = w * 32 + i * 16 + arow;
            int la = __builtin_amdgcn_readfirstlane((w * 32 + i * 16) * 32);
            GLD16(Xs + (rowBase + rl) * (size_t)Crow + cc + aseg * 8, (char*)As + (size_t)la * 2);
        }
#pragma unroll
        for (int i = 0; i < OT / 64; ++i) {
            int rl = w * (OT / 4) + i * 16 + arow;
            int la = __builtin_amdgcn_readfirstlane((w * (OT / 4) + i * 16) * 32);
            GLD16(Wt + (size_t)rl * K + k0 + aseg * 8, (char*)Bs + (size_t)la * 2);
        }
        __syncthreads();
        bf16x8 av[4], bv[JT];
#pragma unroll
        for (int i = 0; i < 4; ++i)
            av[i] = *(const bf16x8*)&As[(wrow * 64 + i * 16 + l16) * 32 + quad * 8];
#pragma unroll
        for (int jj = 0; jj < JT; ++jj)
            bv[jj] = *(const bf16x8*)&Bs[(wcol * JT * 16 + jj * 16 + l16) * 32 + quad * 8];
#pragma unroll
        for (int i = 0; i < 4; ++i)
#pragma unroll
            for (int jj = 0; jj < JT; ++jj)
                acc[i][jj] = SWAP
                    ? __builtin_amdgcn_mfma_f32_16x16x32_bf16(bv[jj], av[i], acc[i][jj], 0, 0, 0)
                    : __builtin_amdgcn_mfma_f32_16x16x32_bf16(av[i], bv[jj], acc[i][jj], 0, 0, 0);
        __syncthreads();
    }
}

// ---------------------------------------------------------------------------
// Epilogue NC (SWAP core): bf16 [B,N,Cout]. acc[i][j]: rows o (quad*4+r),
// cols n (l16). ushort4 writes into LDS tile T[n][o] (stride OT+4), then
// coalesced 16B global stores (full rows of o).
// ---------------------------------------------------------------------------
template<int JT>
__device__ __forceinline__ void epi_nc(
    f32x4 (&acc)[4][JT], const float* __restrict__ bias,
    int b, int n0, int o0, int Cout, u16* __restrict__ outB, u16* T)
{
    constexpr int OT = JT * 32, SP = OT + 4;
    const int tid = threadIdx.x;
    const int lane = tid & 63, w = tid >> 6;
    const int quad = lane >> 4, l16 = lane & 15;
    const int wrow = w & 1, wcol = w >> 1;
    const size_t bN = (size_t)b * NN;

#pragma unroll
    for (int j = 0; j < JT; ++j) {
        int ob = wcol * JT * 16 + j * 16 + quad * 4;
        float4 b4;
        b4.x = bias[o0 + ob + 0]; b4.y = bias[o0 + ob + 1];
        b4.z = bias[o0 + ob + 2]; b4.w = bias[o0 + ob + 3];
#pragma unroll
        for (int i = 0; i < 4; ++i) {
            int nt = wrow * 64 + i * 16 + l16;
            ushort4 pk;
            pk.x = f2b(acc[i][j][0] + b4.x); pk.y = f2b(acc[i][j][1] + b4.y);
            pk.z = f2b(acc[i][j][2] + b4.z); pk.w = f2b(acc[i][j][3] + b4.w);
            *(ushort4*)&T[nt * SP + ob] = pk;
        }
    }
    __syncthreads();
    constexpr int ROWB = OT * 2;                 // data bytes per n-row
    constexpr int RNDS = 128 * ROWB / 4096;
#pragma unroll
    for (int rnd = 0; rnd < RNDS; ++rnd) {
        int linear = rnd * 4096 + tid * 16;
        int nt = linear / ROWB, off = linear % ROWB;
        uint4 v = *(uint4*)&T[nt * SP + off / 2];
        *(uint4*)((char*)&outB[(bN + n0 + nt) * Cout + o0] + off) = v;
    }
}

// ---------------------------------------------------------------------------
// Epilogue V (no-swap core, JT=4): bf16 [B,H,D,N], o=(h<<6)|d. acc rows n,
// cols o. ushort4 writes into T[o][n] (stride 136), coalesced row stores.
// ---------------------------------------------------------------------------
__device__ __forceinline__ void epi_v(
    f32x4 (&acc)[4][4], const float* __restrict__ bias,
    int b, int n0, int o0, u16* __restrict__ outB, u16* T)
{
    const int tid = threadIdx.x;
    const int lane = tid & 63, w = tid >> 6;
    const int quad = lane >> 4, l16 = lane & 15;
    const int wrow = w & 1, wcol = w >> 1;

#pragma unroll
    for (int j = 0; j < 4; ++j) {
        int ot = wcol * 64 + j * 16 + l16;
        float bs = bias[o0 + ot];
#pragma unroll
        for (int i = 0; i < 4; ++i) {
            int nt = wrow * 64 + i * 16 + quad * 4;
            ushort4 pk;
            pk.x = f2b(acc[i][j][0] + bs); pk.y = f2b(acc[i][j][1] + bs);
            pk.z = f2b(acc[i][j][2] + bs); pk.w = f2b(acc[i][j][3] + bs);
            *(ushort4*)&T[ot * 136 + nt] = pk;
        }
    }
    __syncthreads();
#pragma unroll
    for (int rnd = 0; rnd < 8; ++rnd) {
        int linear = rnd * 4096 + tid * 16;
        int ot = linear >> 8, off = linear & 255;
        int o = o0 + ot, h = o >> 6, d = o & 63;
        uint4 v = *(uint4*)&T[ot * 136 + off / 2];
        *(uint4*)((char*)&outB[(((size_t)b * HH + h) * DD + d) * NN + n0] + off) = v;
    }
}

// bf16 [B,N,Cout] GEMM (swapped core + NC epilogue)
template<int JT>
__global__ __launch_bounds__(256, (JT == 2 ? 4 : 3)) void gemm_nc(
    const u16* __restrict__ Wb, const float* __restrict__ bias,
    const u16* __restrict__ Xa, const u16* __restrict__ Xb,
    int Ca, int K, int Cout, u16* __restrict__ outB)
{
    constexpr int SZ = (JT == 2) ? (128 * 68) : (128 * 132);
    __shared__ __align__(16) u16 smem[SZ];
    u16* As = smem; u16* Bs = smem + 4096;
    const int b = blockIdx.z, n0 = blockIdx.x * 128, o0 = blockIdx.y * (JT * 32);
    f32x4 acc[4][JT] = {};
    gemm_core_t<JT, true>(Xa, Xb, Ca, K, Wb + (size_t)o0 * K, (size_t)b * NN + n0, As, Bs, acc);
    epi_nc<JT>(acc, bias, b, n0, o0, Cout, outB, smem);
}

// fp32 [B,Cout,N] = acc+bias+res; mode 2 also bf16 [B,N,Cout] (scalar path)
__global__ __launch_bounds__(256, 4) void gemm_f(
    const u16* __restrict__ Wb, const float* __restrict__ bias,
    const u16* __restrict__ Xa, int K, int Cout,
    const float* __restrict__ res, float* __restrict__ outF,
    u16* __restrict__ outB, int mode)
{
    __shared__ __align__(16) u16 smem[128 * 32 + 64 * 32];
    u16* As = smem; u16* Bs = smem + 4096;
    const int b = blockIdx.z, n0 = blockIdx.x * 128, o0 = blockIdx.y * 64;
    f32x4 acc[4][2] = {};
    gemm_core_t<2, false>(Xa, nullptr, K, K, Wb + (size_t)o0 * K, (size_t)b * NN + n0, As, Bs, acc);

    const int tid = threadIdx.x;
    const int lane = tid & 63, w = tid >> 6;
    const int quad = lane >> 4, l16 = lane & 15;
    const int wrow = w & 1, wcol = w >> 1;
    const size_t bN = (size_t)b * NN;
    const int nb0 = n0 + wrow * 64, ob0 = o0 + wcol * 32;
#pragma unroll
    for (int j = 0; j < 2; ++j) {
        int o = ob0 + j * 16 + l16;
        float bs = bias[o];
#pragma unroll
        for (int i = 0; i < 4; ++i) {
            int n = nb0 + i * 16 + quad * 4;
            size_t ad = ((size_t)b * Cout + o) * NN + n;
            float4 rv = *(const float4*)&res[ad];
            float4 yv;
            yv.x = acc[i][j][0] + bs + rv.x;
            yv.y = acc[i][j][1] + bs + rv.y;
            yv.z = acc[i][j][2] + bs + rv.z;
            yv.w = acc[i][j][3] + bs + rv.w;
            *(float4*)&outF[ad] = yv;
            if (mode == 2) {
                outB[(bN + n + 0) * Cout + o] = f2b(yv.x);
                outB[(bN + n + 1) * Cout + o] = f2b(yv.y);
                outB[(bN + n + 2) * Cout + o] = f2b(yv.z);
                outB[(bN + n + 3) * Cout + o] = f2b(yv.w);
            }
        }
    }
}

// Fused Q+K+V (128-o tiles): yb<4 -> Q; 4..7 -> K; 8..11 -> V ([B,H,D,N]).
__global__ __launch_bounds__(256, 3) void gemm_qkv(
    const u16* __restrict__ WQ, const float* __restrict__ bQ,
    const u16* __restrict__ XQ, u16* __restrict__ outQ,
    const u16* __restrict__ WK, const float* __restrict__ bK, u16* __restrict__ outK,
    const u16* __restrict__ WV, const float* __restrict__ bV, u16* __restrict__ outV,
    const u16* __restrict__ XKV)
{
    __shared__ __align__(16) u16 smem[128 * 136];
    u16* As = smem; u16* Bs = smem + 4096;
    const int yb = blockIdx.y;
    const int b = blockIdx.z, n0 = blockIdx.x * 128;
    if (yb < 8) {
        const u16* W; const float* bias; const u16* X; u16* outB; int o0;
        if (yb < 4) { o0 = yb * 128;       W = WQ; bias = bQ; X = XQ;  outB = outQ; }
        else        { o0 = (yb - 4) * 128; W = WK; bias = bK; X = XKV; outB = outK; }
        f32x4 acc[4][4] = {};
        gemm_core_t<4, true>(X, nullptr, 512, 512, W + (size_t)o0 * 512, (size_t)b * NN + n0, As, Bs, acc);
        epi_nc<4>(acc, bias, b, n0, o0, 512, outB, smem);
    } else {
        int o0 = (yb - 8) * 128;
        f32x4 acc[4][4] = {};
        gemm_core_t<4, false>(XKV, nullptr, 512, 512, WV + (size_t)o0 * 512, (size_t)b * NN + n0, As, Bs, acc);
        epi_v(acc, bV, b, n0, o0, outV, smem);
    }
}

// ---------------------------------------------------------------------------
// Flash attention, MFMA, no max-shift. Q pre-scaled -> p = exp2(s) directly.
// Q,K: [B,N,512] bf16 head-major. V: [B,H,D,N]. Out: [B,N,512].
// 64 q-rows/block, 2 waves x 32 n-cols (ak/vb LDS reads amortize over 2
// n-tiles -> 1.44x less LDS traffic/work). XOR-swizzled 16B granules
// everywhere (conflict-free, no padding). l via P x ones MFMA.
// Grid 1024 linear, XCD-swizzled: each XCD owns 4 whole heads.
// ---------------------------------------------------------------------------
__global__ __launch_bounds__(128, 2) void attn(
    const u16* __restrict__ Qg, const u16* __restrict__ Kg,
    const u16* __restrict__ Vg, u16* __restrict__ Og)
{
    __shared__ __align__(16) u16 Ks[64 * 64];
    __shared__ __align__(16) u16 Vt[64 * 64];
    __shared__ __align__(16) u16 Ps[64 * 64];
    const int tid = threadIdx.x;
    const int lane = tid & 63, w = tid >> 6;          // 2 waves
    const int quad = lane >> 4, l16 = lane & 15;
    const int id = blockIdx.x;
    const int xcd = id & 7, jj = id >> 3;
    const int bh = xcd * 4 + (jj >> 5), nb = jj & 31;
    const int b = bh >> 3, h = bh & 7;
    const int n0 = nb * 64, wn0 = w * 32;
    const size_t qkBase = ((size_t)b * NN) * CC + h * DD;
    const size_t vBase  = (((size_t)b * HH + h) * DD) * NN;
    const int r8 = lane >> 3, seg = lane & 7;
    const int lk = l16 & 7;

    // Q fragments (loop-invariant), B-operand layout: col=n, k=d
    bf16x8 qf[2][2];
#pragma unroll
    for (int ct = 0; ct < 2; ++ct) {
        int n = n0 + wn0 + ct * 16 + l16;
#pragma unroll
        for (int ks = 0; ks < 2; ++ks)
            qf[ct][ks] = *(const bf16x8*)&Qg[qkBase + (size_t)n * CC + ks * 32 + quad * 8];
    }

    const short oneb = 0x3F80;
    const bf16x8 ones = {oneb, oneb, oneb, oneb, oneb, oneb, oneb, oneb};
    f32x4 oa[2][4] = {};
    f32x4 lacc[2] = {};

    for (int m0 = 0; m0 < NN; m0 += 64) {
        // swizzled direct-to-LDS staging: each wave stages 32 rows of K and V
#pragma unroll
        for (int it = 0; it < 4; ++it) {
            int rowb = wn0 + it * 8;
            int segp = seg ^ r8;
            GLD16(&Kg[qkBase + (size_t)(m0 + rowb + r8) * CC + segp * 8], &Ks[rowb * 64]);
            GLD16(&Vg[vBase + (size_t)(rowb + r8) * NN + m0 + segp * 8], &Vt[rowb * 64]);
        }
        __syncthreads();

        // S^T = K * Q^T : rows m (4 tiles), cols n (2 tiles/wave)
        f32x4 st[4][2] = {};
#pragma unroll
        for (int ks = 0; ks < 2; ++ks) {
            bf16x8 ak[4];
#pragma unroll
            for (int rt = 0; rt < 4; ++rt)
                ak[rt] = *(const bf16x8*)&Ks[(rt * 16 + l16) * 64 + ((ks * 4 + quad) ^ lk) * 8];
#pragma unroll
            for (int rt = 0; rt < 4; ++rt)
#pragma unroll
                for (int ct = 0; ct < 2; ++ct)
                    st[rt][ct] = __builtin_amdgcn_mfma_f32_16x16x32_bf16(ak[rt], qf[ct][ks], st[rt][ct], 0, 0, 0);
        }

        // p = exp2(s), truncate-pack via v_perm, store P[n][m] swizzled
#pragma unroll
        for (int ct = 0; ct < 2; ++ct) {
            int nrow = wn0 + ct * 16 + l16;
#pragma unroll
            for (int rt = 0; rt < 4; ++rt) {
                unsigned u0 = __builtin_bit_cast(unsigned, __ocml_exp2_f32(st[rt][ct][0]));
                unsigned u1 = __builtin_bit_cast(unsigned, __ocml_exp2_f32(st[rt][ct][1]));
                unsigned u2 = __builtin_bit_cast(unsigned, __ocml_exp2_f32(st[rt][ct][2]));
                unsigned u3 = __builtin_bit_cast(unsigned, __ocml_exp2_f32(st[rt][ct][3]));
                uint2 t;
                t.x = __builtin_amdgcn_perm(u1, u0, 0x07060302u);
                t.y = __builtin_amdgcn_perm(u3, u2, 0x07060302u);
                int g = (rt * 2 + (quad >> 1)) ^ lk;
                *(uint2*)&Ps[nrow * 64 + g * 8 + (quad & 1) * 4] = t;
            }
        }

        // O += P * V^T ; l += P * ones  (own wave's P rows, no barrier)
#pragma unroll
        for (int ks = 0; ks < 2; ++ks) {
            bf16x8 vb[4];
#pragma unroll
            for (int dt = 0; dt < 4; ++dt)
                vb[dt] = *(const bf16x8*)&Vt[(dt * 16 + l16) * 64 + ((ks * 4 + quad) ^ lk) * 8];
#pragma unroll
            for (int ct = 0; ct < 2; ++ct) {
                bf16x8 pa = *(const bf16x8*)&Ps[(wn0 + ct * 16 + l16) * 64 + ((ks * 4 + quad) ^ lk) * 8];
#pragma unroll
                for (int dt = 0; dt < 4; ++dt)
                    oa[ct][dt] = __builtin_amdgcn_mfma_f32_16x16x32_bf16(pa, vb[dt], oa[ct][dt], 0, 0, 0);
                lacc[ct] = __builtin_amdgcn_mfma_f32_16x16x32_bf16(pa, ones, lacc[ct], 0, 0, 0);
            }
        }
        __syncthreads();
    }

#pragma unroll
    for (int ct = 0; ct < 2; ++ct)
#pragma unroll
        for (int r = 0; r < 4; ++r) {
            float li = 1.f / lacc[ct][r];
            int n = n0 + wn0 + ct * 16 + quad * 4 + r;
#pragma unroll
            for (int dt = 0; dt < 4; ++dt)
                Og[qkBase + (size_t)n * CC + dt * 16 + l16] = f2b(oa[ct][dt][r] * li);
        }
}

// ---------------------------------------------------------------------------
// fp32 [B,C,N] -> bf16 [B,N,C] transpose+convert (64x64 tiles via LDS)
// ---------------------------------------------------------------------------
__global__ __launch_bounds__(256) void transpose_cvt(
    const float* __restrict__ X, u16* __restrict__ Y)
{
    __shared__ float T[64][65];
    const int tid = threadIdx.x;
    const int n0 = blockIdx.x * 64, c0 = blockIdx.y * 64, b = blockIdx.z;
    const int rr = tid >> 4, cc4 = tid & 15;
#pragma unroll
    for (int p = 0; p < 4; ++p) {
        int cl = p * 16 + rr;
        float4 v = *(const float4*)&X[((size_t)b * CC + c0 + cl) * NN + n0 + cc4 * 4];
        T[cl][cc4 * 4 + 0] = v.x; T[cl][cc4 * 4 + 1] = v.y;
        T[cl][cc4 * 4 + 2] = v.z; T[cl][cc4 * 4 + 3] = v.w;
    }
    __syncthreads();
#pragma unroll
    for (int p = 0; p < 4; ++p) {
        int nl = p * 16 + rr;
        ushort4 pk;
        pk.x = f2b(T[cc4 * 4 + 0][nl]);
        pk.y = f2b(T[cc4 * 4 + 1][nl]);
        pk.z = f2b(T[cc4 * 4 + 2][nl]);
        pk.w = f2b(T[cc4 * 4 + 3][nl]);
        *(ushort4*)&Y[((size_t)b * NN + n0 + nl) * CC + c0 + cc4 * 4] = pk;
    }
}

// ---------------------------------------------------------------------------
// Weight prep: fp32->bf16, optional head row/col permute + scale.
// z: 0=Wq(perm1,xSCALE) 1=Wk(perm1) 2=Wv(perm1) 3=Wm(perm2) 4=W1 5=W2
// ---------------------------------------------------------------------------
__global__ __launch_bounds__(256) void prep_weights(
    const float* __restrict__ Wq, const float* __restrict__ Wk,
    const float* __restrict__ Wv, const float* __restrict__ Wm,
    const float* __restrict__ W1, const float* __restrict__ W2,
    u16* oQ, u16* oK, u16* oV, u16* oM, u16* o1, u16* o2)
{
    const float* W; u16* o; int rows, cols, perm; float sc = 1.f;
    switch (blockIdx.z) {
        case 0: W = Wq; o = oQ; rows = 512;  cols = 512;  perm = 1; sc = SCALE; break;
        case 1: W = Wk; o = oK; rows = 512;  cols = 512;  perm = 1; break;
        case 2: W = Wv; o = oV; rows = 512;  cols = 512;  perm = 1; break;
        case 3: W = Wm; o = oM; rows = 512;  cols = 512;  perm = 2; break;
        case 4: W = W1; o = o1; rows = 1024; cols = 1024; perm = 0; break;
        default: W = W2; o = o2; rows = 512; cols = 1024; perm = 0; break;
    }
    int c = blockIdx.x * 256 + threadIdx.x;
    int r = blockIdx.y;
    if (r >= rows || c >= cols) return;
    int sr = r, scol = c;
    if (perm == 1) sr = (r & 63) * 8 + (r >> 6);
    else if (perm == 2) scol = (c & 63) * 8 + (c >> 6);
    o[(size_t)r * cols + c] = f2b(W[(size_t)sr * cols + scol] * sc);
}

__global__ void prep_bias(const float* __restrict__ bq, const float* __restrict__ bk,
                          const float* __restrict__ bv,
                          float* oq, float* ok, float* ov)
{
    int i = blockIdx.x * 256 + threadIdx.x;
    int y = blockIdx.y;
    const float* s = (y == 0) ? bq : (y == 1) ? bk : bv;
    float* o = (y == 0) ? oq : (y == 1) ? ok : ov;
    float v = s[(i & 63) * 8 + (i >> 6)];
    if (y == 0) v *= SCALE;
    o[i] = v;
}

// ---------------------------------------------------------------------------
// Instance norm over N per (b,c) on bf16 [B,N,1024], two-pass via fp32 atomics
// ---------------------------------------------------------------------------
__global__ __launch_bounds__(256) void inorm_p1(
    const u16* __restrict__ X, float* __restrict__ Ssum, float* __restrict__ Ssq)
{
    __shared__ float rs[4][64], rq[4][64];
    const int tid = threadIdx.x;
    const int cl = tid & 63, g = tid >> 6;
    const int c = blockIdx.x * 64 + cl;
    const int b = blockIdx.y, nz = blockIdx.z;
    float s = 0.f, q = 0.f;
    size_t base = ((size_t)b * NN + nz * 256 + g * 64) * 1024 + c;
#pragma unroll 4
    for (int i = 0; i < 64; ++i) {
        float x = b2f(X[base + (size_t)i * 1024]);
        s += x; q += x * x;
    }
    rs[g][cl] = s; rq[g][cl] = q;
    __syncthreads();
    if (g == 0) {
        s = rs[0][cl] + rs[1][cl] + rs[2][cl] + rs[3][cl];
        q = rq[0][cl] + rq[1][cl] + rq[2][cl] + rq[3][cl];
        atomicAdd(&Ssum[b * 1024 + c], s);
        atomicAdd(&Ssq[b * 1024 + c], q);
    }
}

__global__ __launch_bounds__(256) void inorm_p2(
    u16* __restrict__ X, const float* __restrict__ Ssum, const float* __restrict__ Ssq)
{
    const int tid = threadIdx.x;
    const int cl = tid & 63, g = tid >> 6;
    const int c = blockIdx.x * 64 + cl;
    const int b = blockIdx.y, nz = blockIdx.z;
    float mean = Ssum[b * 1024 + c] * (1.f / NN);
    float var  = Ssq[b * 1024 + c] * (1.f / NN) - mean * mean;
    float rstd = rsqrtf(fmaxf(var, 0.f) + 1e-5f);
    size_t base = ((size_t)b * NN + nz * 256 + g * 64) * 1024 + c;
#pragma unroll 4
    for (int i = 0; i < 64; ++i) {
        float x = b2f(X[base + (size_t)i * 1024]);
        x = (x - mean) * rstd;
        X[base + (size_t)i * 1024] = f2b(fmaxf(x, 0.f));
    }
}

// ---------------------------------------------------------------------------
extern "C" void kernel_launch(void* const* d_in, const int* in_sizes, int n_in,
                              void* d_out, int out_size, void* d_ws, size_t ws_size,
                              hipStream_t stream)
{
    (void)in_sizes; (void)n_in; (void)out_size; (void)ws_size;
    const float* src = (const float*)d_in[0];
    const float* tgt = (const float*)d_in[1];
    const float* Wq = (const float*)d_in[2];  const float* bq = (const float*)d_in[3];
    const float* Wk = (const float*)d_in[4];  const float* bk = (const float*)d_in[5];
    const float* Wv = (const float*)d_in[6];  const float* bv = (const float*)d_in[7];
    const float* Wm = (const float*)d_in[8];  const float* bm = (const float*)d_in[9];
    const float* W1 = (const float*)d_in[10]; const float* b1 = (const float*)d_in[11];
    const float* W2 = (const float*)d_in[12]; const float* b2 = (const float*)d_in[13];

    char* w = (char*)d_ws;
    u16* WQp = (u16*)(w);
    u16* WKp = (u16*)(w + (512u << 10));
    u16* WVp = (u16*)(w + (1u << 20));
    u16* WMp = (u16*)(w + (3u << 19));
    u16* W1b = (u16*)(w + (2u << 20));
    u16* W2b = (u16*)(w + (4u << 20));
    float* BQp = (float*)(w + (5u << 20));
    float* BKp = BQp + 512;
    float* BVp = BQp + 1024;
    float* STS = BQp + 1536;
    float* STQ = STS + 4096;
    u16* X0 = (u16*)(w + ( 6u << 20));        // 8 MB regions
    u16* X1 = (u16*)(w + (14u << 20));
    u16* B0 = (u16*)(w + (22u << 20));
    u16* B1 = (u16*)(w + (30u << 20));        // B1+B2 contiguous = 16 MB hid
    u16* B2 = (u16*)(w + (38u << 20));
    u16* B3 = (u16*)(w + (46u << 20));

    float* out = (float*)d_out;
    const size_t R = (size_t)BB * CC * NN;
    dim3 blk(256);

    prep_weights<<<dim3(4, 1024, 6), blk, 0, stream>>>(Wq, Wk, Wv, Wm, W1, W2,
                                                       WQp, WKp, WVp, WMp, W1b, W2b);
    prep_bias<<<dim3(2, 3), blk, 0, stream>>>(bq, bk, bv, BQp, BKp, BVp);
    transpose_cvt<<<dim3(32, 8, 4), blk, 0, stream>>>(src, X0);
    transpose_cvt<<<dim3(32, 8, 4), blk, 0, stream>>>(tgt, X1);

    dim3 gQKV(16, 12, 4), gM(16, 8, 4), gW1(16, 8, 4), gW2(16, 8, 4);

    // ---- pipeline 1: q<-src(X0), k/v<-tgt(X1), residual=src ----
    gemm_qkv<<<gQKV, blk, 0, stream>>>(WQp, BQp, X0, B0, WKp, BKp, B1, WVp, BVp, B2, X1);
    attn<<<dim3(1024), dim3(128), 0, stream>>>(B0, B1, B2, B3);
    gemm_nc<2><<<gM, blk, 0, stream>>>(WMp, bm, B3, nullptr, 512, 512, 512, B0);
    gemm_nc<4><<<gW1, blk, 0, stream>>>(W1b, b1, X0, B0, 512, 1024, 1024, B1);
    hipMemsetAsync(STS, 0, 8192 * sizeof(float), stream);
    inorm_p1<<<dim3(16, 4, 8), blk, 0, stream>>>(B1, STS, STQ);
    inorm_p2<<<dim3(16, 4, 8), blk, 0, stream>>>(B1, STS, STQ);
    gemm_f<<<gW2, blk, 0, stream>>>(W2b, b2, B1, 1024, 512, src, out, B3, 2);

    // ---- pipeline 2: q<-tgt(X1), k/v<-src_new(B3), residual=tgt ----
    gemm_qkv<<<gQKV, blk, 0, stream>>>(WQp, BQp, X1, X0, WKp, BKp, B0, WVp, BVp, B1, B3);
    attn<<<dim3(1024), dim3(128), 0, stream>>>(X0, B0, B1, B2);
    gemm_nc<2><<<gM, blk, 0, stream>>>(WMp, bm, B2, nullptr, 512, 512, 512, X0);
    gemm_nc<4><<<gW1, blk, 0, stream>>>(W1b, b1, X1, X0, 512, 1024, 1024, B0);
    hipMemsetAsync(STS, 0, 8192 * sizeof(float), stream);
    inorm_p1<<<dim3(16, 4, 8), blk, 0, stream>>>(B0, STS, STQ);
    inorm_p2<<<dim3(16, 4, 8), blk, 0, stream>>>(B0, STS, STQ);
    gemm_f<<<gW2, blk, 0, stream>>>(W2b, b2, B0, 1024, 512, tgt, out + R, nullptr, 3);
}